// Round 6
// baseline (348.490 us; speedup 1.0000x reference)
//
#include <hip/hip_runtime.h>
#include <hip/hip_bf16.h>

// Problem constants
#define BB 2
#define SS 2048
#define DD 1024
#define HH 16
#define HD 64
#define NREL 129
#define LOG2E 1.4426950408889634f
#define SCALEQ (LOG2E / 8.0f)   // folded into Q at projection time
#define KVB 131072l              // elems per bh in ktile/vtile (32*8*64*8)

typedef short s8v __attribute__((ext_vector_type(8)));
typedef short s4v __attribute__((ext_vector_type(4)));
typedef float f4 __attribute__((ext_vector_type(4)));

#define MFMA_BF16 __builtin_amdgcn_mfma_f32_16x16x32_bf16

__device__ __forceinline__ float bf2f(unsigned short u) {
  union { unsigned int i; float f; } x; x.i = ((unsigned int)u) << 16; return x.f;
}
__device__ __forceinline__ unsigned short f2bf(float f) {
  union { float f; unsigned int i; } x; x.f = f;
  unsigned int r = x.i + 0x7fffu + ((x.i >> 16) & 1u);
  return (unsigned short)(r >> 16);
}
__device__ __forceinline__ unsigned int pk2bf(float a, float b) {
  union { __hip_bfloat162 h2; unsigned int u; } c;
  c.h2 = __float22bfloat162_rn(float2{a, b});
  return c.u;
}
// async global->LDS DMA, 16B/lane; global src MUST be lane-contiguous for
// coalescing; LDS dest = base + lane*16 (used by proj_gemm only now)
__device__ __forceinline__ void gl_lds16(const void* g, void* l) {
  __builtin_amdgcn_global_load_lds(
      (const __attribute__((address_space(1))) unsigned int*)g,
      (__attribute__((address_space(3))) unsigned int*)l, 16, 0, 0);
}

// ---------------------------------------------------------------------------
// fp32 -> bf16 convert of the 3 input tensors [4096][1024] -> xb [3][4096*1024]
__global__ __launch_bounds__(256) void cvt_x(
    const float* __restrict__ xq, const float* __restrict__ xk,
    const float* __restrict__ xv, unsigned short* __restrict__ xb) {
  const int z = blockIdx.y;
  const float* in = (z == 0) ? xq : (z == 1) ? xk : xv;
  unsigned short* out = xb + (long)z * 4096 * DD;
  const long i = ((long)blockIdx.x * 256 + threadIdx.x) * 8;
  f4 a = *(const f4*)(in + i);
  f4 b = *(const f4*)(in + i + 4);
  unsigned int u[4];
  u[0] = pk2bf(a[0], a[1]); u[1] = pk2bf(a[2], a[3]);
  u[2] = pk2bf(b[0], b[1]); u[3] = pk2bf(b[2], b[3]);
  *(s8v*)(out + i) = *(s8v*)u;
}

// ---------------------------------------------------------------------------
// Weight transpose+convert to TILED layout:
// WTt[z][n0g(8)][k0g(16)][kc(8)][n(128)][8k] — 16 KB per (n0,k0) tile,
// byte-image of proj_gemm's LDS tile. grid (16, 16, 3), block 256.
__global__ __launch_bounds__(256) void cvt_w(
    const float* __restrict__ Wq, const float* __restrict__ Wk,
    const float* __restrict__ Wv, unsigned short* __restrict__ WTt) {
  __shared__ unsigned short tile[64][72];
  const int z = blockIdx.z;
  const float* in = (z == 0) ? Wq : (z == 1) ? Wk : Wv;
  unsigned short* out = WTt + (long)z * 1048576;
  const int c0 = blockIdx.x * 64, r0 = blockIdx.y * 64;  // c0: n-base, r0: k-base
  const int t = threadIdx.x;
  const int r = t >> 2;
  #pragma unroll
  for (int j = 0; j < 4; ++j) {
    int cc = (t & 3) * 16 + j * 4;
    f4 v = *(const f4*)(in + (long)(r0 + r) * DD + c0 + cc);
    #pragma unroll
    for (int e = 0; e < 4; ++e) tile[r][cc + e] = f2bf(v[e]);
  }
  __syncthreads();
  const int c = t >> 2;           // n within 64-tile
  #pragma unroll
  for (int h = 0; h < 2; ++h) {
    int r8 = (t & 3) + 4 * h;     // k-octet within 64-tile
    unsigned short vals[8];
    #pragma unroll
    for (int j = 0; j < 8; ++j) vals[j] = tile[r8 * 8 + j][c];
    int n = c0 + c, kb = r0 + r8 * 8;
    long off = ((long)(n >> 7) * 131072) + ((kb >> 6) * 8192) +
               (((kb & 63) >> 3) * 1024) + ((n & 127) * 8);
    *(s8v*)(out + off) = *(s8v*)vals;
  }
}

// ---------------------------------------------------------------------------
// Fused QKV projection GEMM: C = Xb @ W + bias.
// Q head-split [bh][s][d] (pre-scaled); K -> ktile[bh][g][c][key][8];
// V -> vtile[bh][g][c][d][8]. grid (8 n, 32 m, 3 z), block 256.
__global__ __launch_bounds__(256, 4) void proj_gemm(
    const unsigned short* __restrict__ Xb, const unsigned short* __restrict__ WTt,
    const float* __restrict__ bq, const float* __restrict__ bk,
    const float* __restrict__ bv,
    unsigned short* __restrict__ qbuf, unsigned short* __restrict__ ktile,
    unsigned short* __restrict__ vtile) {
  __shared__ __align__(16) unsigned short wt[8][128][8];  // [kc][n][8k] 16KB
  unsigned short* wtf = &wt[0][0][0];
  const int z = blockIdx.z;
  const unsigned short* X = Xb + (long)z * 4096 * DD;
  const unsigned short* WTz = WTt + (long)z * 1048576;
  const float* bias = (z == 0) ? bq : (z == 1) ? bk : bv;

  const int n0 = blockIdx.x * 128, m0 = blockIdx.y * 128;
  const int t = threadIdx.x, w = t >> 6, l = t & 63;
  const int lm = l & 15, qd = l >> 4;

  f4 acc[8][2];
  #pragma unroll
  for (int i = 0; i < 8; ++i) { acc[i][0] = (f4)0.0f; acc[i][1] = (f4)0.0f; }

  const unsigned short* x0 = X + (long)(m0 + w * 32 + lm) * DD;
  const unsigned short* x1 = x0 + 16 * DD;
  const unsigned short* wtile0 = WTz + (long)(n0 >> 7) * 131072;

  for (int k0 = 0; k0 < DD; k0 += 64) {
    __syncthreads();   // all waves done reading wt from previous iter
    // stage 16 KB WT tile: 16 lane-contiguous 1KB DMA bursts
    const unsigned short* tb = wtile0 + (k0 >> 6) * 8192;
    #pragma unroll
    for (int i = 0; i < 4; ++i) {
      int idx = w * 4 + i;
      gl_lds16(tb + idx * 512 + l * 8, wtf + idx * 512);
    }
    // A fragments direct from bf16 global (L2-served)
    s8v a00 = *(const s8v*)(x0 + k0 + qd * 8);
    s8v a01 = *(const s8v*)(x0 + k0 + 32 + qd * 8);
    s8v a10 = *(const s8v*)(x1 + k0 + qd * 8);
    s8v a11 = *(const s8v*)(x1 + k0 + 32 + qd * 8);
    asm volatile("s_waitcnt vmcnt(0)" ::: "memory");
    __syncthreads();   // DMA landed for all waves
    #pragma unroll
    for (int cb = 0; cb < 8; ++cb) {
      s8v b0 = *(const s8v*)&wt[qd][cb * 16 + lm][0];
      s8v b1 = *(const s8v*)&wt[4 + qd][cb * 16 + lm][0];
      acc[cb][0] = MFMA_BF16(a00, b0, acc[cb][0], 0, 0, 0);
      acc[cb][0] = MFMA_BF16(a01, b1, acc[cb][0], 0, 0, 0);
      acc[cb][1] = MFMA_BF16(a10, b0, acc[cb][1], 0, 0, 0);
      acc[cb][1] = MFMA_BF16(a11, b1, acc[cb][1], 0, 0, 0);
    }
  }
  if (z == 0) {
    // Q: head-split [bh][s][d], pre-scaled
    #pragma unroll
    for (int cb = 0; cb < 8; ++cb) {
      int n = n0 + cb * 16 + lm;
      float bvv = bias[n];
      int hh = n >> 6, d = n & 63;
      #pragma unroll
      for (int ms = 0; ms < 2; ++ms) {
        #pragma unroll
        for (int r = 0; r < 4; ++r) {
          int m = m0 + w * 32 + ms * 16 + qd * 4 + r;
          int bidx = m >> 11, s = m & (SS - 1);
          qbuf[((long)(bidx * HH + hh) * SS + s) * HD + d] =
              f2bf((acc[cb][ms][r] + bvv) * SCALEQ);
        }
      }
    }
  } else if (z == 1) {
    // K -> ktile[bh][g][c][key][8]
    #pragma unroll
    for (int cb = 0; cb < 8; ++cb) {
      int n = n0 + cb * 16 + lm;
      float bvv = bias[n];
      int hh = n >> 6, d = n & 63;
      int c = d >> 3, e = d & 7;
      #pragma unroll
      for (int ms = 0; ms < 2; ++ms) {
        #pragma unroll
        for (int r = 0; r < 4; ++r) {
          int m = m0 + w * 32 + ms * 16 + qd * 4 + r;
          int bidx = m >> 11, s = m & (SS - 1);
          long bh = bidx * HH + hh;
          ktile[bh * KVB + (s >> 6) * 4096 + c * 512 + (s & 63) * 8 + e] =
              f2bf(acc[cb][ms][r] + bvv);
        }
      }
    }
  } else {
    // V -> vtile[bh][g][c][d][8], 4 consecutive s per 8B store
    #pragma unroll
    for (int cb = 0; cb < 8; ++cb) {
      int n = n0 + cb * 16 + lm;
      float bvv = bias[n];
      int hh = n >> 6, d = n & 63;
      #pragma unroll
      for (int ms = 0; ms < 2; ++ms) {
        int m = m0 + w * 32 + ms * 16 + qd * 4;
        int bidx = m >> 11, s = m & (SS - 1);
        long bh = bidx * HH + hh;
        unsigned short o4[4];
        #pragma unroll
        for (int r = 0; r < 4; ++r) o4[r] = f2bf(acc[cb][ms][r] + bvv);
        *(s4v*)&vtile[bh * KVB + (s >> 6) * 4096 + ((s & 63) >> 3) * 512 +
                      d * 8 + (s & 7)] = *(s4v*)o4;
      }
    }
  }
}

// ---------------------------------------------------------------------------
// Flash attention. 2 q-subtiles per wave (32 q/wave, 128 q/block).
// K/V are NOT staged in LDS: per-bh K/V (512 KB) is L2-resident and all 4
// waves read identical addresses (L1 x4 reuse) — fragments load straight
// from global into registers, double-buffered across iterations (even/odd
// unroll keeps all indexing static). This removes every main-loop barrier
// and vmcnt drain; the block's 8 waves/CU free-run and overlap stalls.
// qrel + mask stay in LDS (round-3-proven). Merged pbuf rounds: 2 lgkmcnt
// drains/iter instead of 4. grid (16 q-blocks, 32 bh), block 256.

// load K/V register fragments for key-group RR (8 frags each, 4 VGPR/frag)
#define LOADKV(RR, K, V) do {                                                \
    const unsigned short* kg_ = kkb + (RR) * 4096;                           \
    const unsigned short* vg_ = vvb + (RR) * 4096;                           \
    _Pragma("unroll")                                                        \
    for (int tt = 0; tt < 4; ++tt) {                                         \
      K[tt]     = *(const s8v*)(kg_ + qd * 512 + (tt * 16 + lm) * 8);        \
      K[4 + tt] = *(const s8v*)(kg_ + (4 + qd) * 512 + (tt * 16 + lm) * 8);  \
      V[tt]     = *(const s8v*)(vg_ + qd * 512 + (tt * 16 + lm) * 8);        \
      V[4 + tt] = *(const s8v*)(vg_ + (4 + qd) * 512 + (tt * 16 + lm) * 8);  \
    }                                                                        \
  } while (0)

#define ATTN_STEP(RR, CK, CV, NK, NV, DONEXT) do {                           \
    const int kk = (RR) << 6;                                                \
    if (DONEXT) { LOADKV((RR) + 1, NK, NV); }                                \
    f4 st0[4], st1[4];                                                       \
    _Pragma("unroll")                                                        \
    for (int tt = 0; tt < 4; ++tt) {                                         \
      st0[tt] = MFMA_BF16(CK[tt], qa0, (f4)0.0f, 0, 0, 0);                   \
      st0[tt] = MFMA_BF16(CK[4 + tt], qa1, st0[tt], 0, 0, 0);                \
      st1[tt] = MFMA_BF16(CK[tt], qb0, (f4)0.0f, 0, 0, 0);                   \
      st1[tt] = MFMA_BF16(CK[4 + tt], qb1, st1[tt], 0, 0, 0);                \
    }                                                                        \
    float z0[16], z1[16];                                                    \
    const int kw = kk - qw;                                                  \
    if (kw >= 96) {                                                          \
      _Pragma("unroll")                                                      \
      for (int tt = 0; tt < 4; ++tt) {                                       \
        f4 mv = *(const f4*)&mk[kk + tt * 16 + qd * 4];                      \
        _Pragma("unroll")                                                    \
        for (int r = 0; r < 4; ++r) {                                        \
          z0[tt * 4 + r] = st0[tt][r] + bHi0 + mv[r];                        \
          z1[tt * 4 + r] = st1[tt][r] + bHi1 + mv[r];                        \
        }                                                                    \
      }                                                                      \
    } else if (kw <= -128) {                                                 \
      _Pragma("unroll")                                                      \
      for (int tt = 0; tt < 4; ++tt) {                                       \
        f4 mv = *(const f4*)&mk[kk + tt * 16 + qd * 4];                      \
        _Pragma("unroll")                                                    \
        for (int r = 0; r < 4; ++r) {                                        \
          z0[tt * 4 + r] = st0[tt][r] + bLo0 + mv[r];                        \
          z1[tt * 4 + r] = st1[tt][r] + bLo1 + mv[r];                        \
        }                                                                    \
      }                                                                      \
    } else {                                                                 \
      const int db0 = kw - lm + 64 + qd * 4;                                 \
      _Pragma("unroll")                                                      \
      for (int tt = 0; tt < 4; ++tt) {                                       \
        f4 mv = *(const f4*)&mk[kk + tt * 16 + qd * 4];                      \
        _Pragma("unroll")                                                    \
        for (int r = 0; r < 4; ++r) {                                        \
          int du = db0 + tt * 16 + r;                                        \
          int d0 = du < 0 ? 0 : (du > 128 ? 128 : du);                       \
          int d1 = du - 16; d1 = d1 < 0 ? 0 : (d1 > 128 ? 128 : d1);         \
          z0[tt * 4 + r] = st0[tt][r] + bf2f(qr2[d0][qc0]) + mv[r];          \
          z1[tt * 4 + r] = st1[tt][r] + bf2f(qr2[d1][qc1]) + mv[r];          \
        }                                                                    \
      }                                                                      \
    }                                                                        \
    float tm0 = z0[0], tm1 = z1[0];                                          \
    _Pragma("unroll")                                                        \
    for (int i = 1; i < 16; ++i) {                                           \
      tm0 = fmaxf(tm0, z0[i]);                                               \
      tm1 = fmaxf(tm1, z1[i]);                                               \
    }                                                                        \
    tm0 = fmaxf(tm0, __shfl_xor(tm0, 16));                                   \
    tm0 = fmaxf(tm0, __shfl_xor(tm0, 32));                                   \
    tm1 = fmaxf(tm1, __shfl_xor(tm1, 16));                                   \
    tm1 = fmaxf(tm1, __shfl_xor(tm1, 32));                                   \
    float mn0 = fmaxf(m0_, tm0), mn1 = fmaxf(m1_, tm1);                      \
    float al0 = __builtin_amdgcn_exp2f(m0_ - mn0);                           \
    float al1 = __builtin_amdgcn_exp2f(m1_ - mn1);                           \
    m0_ = mn0; m1_ = mn1;                                                    \
    float s0 = 0.0f, s1 = 0.0f;                                              \
    _Pragma("unroll")                                                        \
    for (int i = 0; i < 16; ++i) {                                           \
      z0[i] = __builtin_amdgcn_exp2f(z0[i] - mn0); s0 += z0[i];              \
      z1[i] = __builtin_amdgcn_exp2f(z1[i] - mn1); s1 += z1[i];              \
    }                                                                        \
    s0 += __shfl_xor(s0, 16);                                                \
    s0 += __shfl_xor(s0, 32);                                                \
    s1 += __shfl_xor(s1, 16);                                                \
    s1 += __shfl_xor(s1, 32);                                                \
    l0_ = l0_ * al0 + s0; l1_ = l1_ * al1 + s1;                              \
    _Pragma("unroll")                                                        \
    for (int db = 0; db < 4; ++db)                                           \
      _Pragma("unroll")                                                      \
      for (int r = 0; r < 4; ++r) { c40[db][r] *= al0; c41[db][r] *= al1; }  \
    /* PV phase A (keys 0..31): merged round, one drain for both subtiles */ \
    *(unsigned int*)&pb0[w][lm][qd * 4]          = pk2bf(z0[0], z0[1]);      \
    *(unsigned int*)&pb0[w][lm][qd * 4 + 2]      = pk2bf(z0[2], z0[3]);      \
    *(unsigned int*)&pb0[w][lm][16 + qd * 4]     = pk2bf(z0[4], z0[5]);      \
    *(unsigned int*)&pb0[w][lm][16 + qd * 4 + 2] = pk2bf(z0[6], z0[7]);      \
    *(unsigned int*)&pb1[w][lm][qd * 4]          = pk2bf(z1[0], z1[1]);      \
    *(unsigned int*)&pb1[w][lm][qd * 4 + 2]      = pk2bf(z1[2], z1[3]);      \
    *(unsigned int*)&pb1[w][lm][16 + qd * 4]     = pk2bf(z1[4], z1[5]);      \
    *(unsigned int*)&pb1[w][lm][16 + qd * 4 + 2] = pk2bf(z1[6], z1[7]);      \
    asm volatile("s_waitcnt lgkmcnt(0)" ::: "memory");                       \
    {                                                                        \
      s8v pa0 = *(const s8v*)&pb0[w][lm][qd * 8];                            \
      s8v pa1 = *(const s8v*)&pb1[w][lm][qd * 8];                            \
      _Pragma("unroll")                                                      \
      for (int db = 0; db < 4; ++db) {                                       \
        c40[db] = MFMA_BF16(CV[db], pa0, c40[db], 0, 0, 0);                  \
        c41[db] = MFMA_BF16(CV[db], pa1, c41[db], 0, 0, 0);                  \
      }                                                                      \
    }                                                                        \
    /* PV phase B (keys 32..63) */                                           \
    *(unsigned int*)&pb0[w][lm][qd * 4]          = pk2bf(z0[8], z0[9]);      \
    *(unsigned int*)&pb0[w][lm][qd * 4 + 2]      = pk2bf(z0[10], z0[11]);    \
    *(unsigned int*)&pb0[w][lm][16 + qd * 4]     = pk2bf(z0[12], z0[13]);    \
    *(unsigned int*)&pb0[w][lm][16 + qd * 4 + 2] = pk2bf(z0[14], z0[15]);    \
    *(unsigned int*)&pb1[w][lm][qd * 4]          = pk2bf(z1[8], z1[9]);      \
    *(unsigned int*)&pb1[w][lm][qd * 4 + 2]      = pk2bf(z1[10], z1[11]);    \
    *(unsigned int*)&pb1[w][lm][16 + qd * 4]     = pk2bf(z1[12], z1[13]);    \
    *(unsigned int*)&pb1[w][lm][16 + qd * 4 + 2] = pk2bf(z1[14], z1[15]);    \
    asm volatile("s_waitcnt lgkmcnt(0)" ::: "memory");                       \
    {                                                                        \
      s8v pb0v = *(const s8v*)&pb0[w][lm][qd * 8];                           \
      s8v pb1v = *(const s8v*)&pb1[w][lm][qd * 8];                           \
      _Pragma("unroll")                                                      \
      for (int db = 0; db < 4; ++db) {                                       \
        c40[db] = MFMA_BF16(CV[4 + db], pb0v, c40[db], 0, 0, 0);             \
        c41[db] = MFMA_BF16(CV[4 + db], pb1v, c41[db], 0, 0, 0);             \
      }                                                                      \
    }                                                                        \
  } while (0)

__global__ __launch_bounds__(256, 2) void attn(
    const unsigned short* __restrict__ qb, const unsigned short* __restrict__ ktile,
    const unsigned short* __restrict__ vtile, const float* __restrict__ tableF,
    const float* __restrict__ maskF, float* __restrict__ out) {
  __shared__ __align__(16) unsigned short qr2[NREL][130];  // [dist][q_local+pad]
  __shared__ __align__(16) unsigned short pb0[4][16][40];  // per-wave P, sub0
  __shared__ __align__(16) unsigned short pb1[4][16][40];  // per-wave P, sub1
  __shared__ float mk[SS];                                 // mask*LOG2E

  const int bh = blockIdx.y, b = bh >> 4, h = bh & 15;
  const int q0 = blockIdx.x * 128;
  const int t = threadIdx.x, w = t >> 6, l = t & 63;
  const int lm = l & 15, qd = l >> 4;
  const int qw = q0 + w * 32;          // this wave's q base (32 rows)
  const int qc0 = w * 32 + lm, qc1 = qc0 + 16;  // local q cols of the 2 subtiles

  const unsigned short* kkb = ktile + (long)bh * KVB;
  const unsigned short* vvb = vtile + (long)bh * KVB;

  // K/V register double-buffers; issue group-0 loads first so they complete
  // under the qrel MFMA phase.
  s8v K0[8], V0[8], K1[8], V1[8];
  LOADKV(0, K0, V0);

  // stage mask (pre-scaled by LOG2E)
  {
    const float* mrow = maskF + b * SS;
    f4 m0v = *(const f4*)(mrow + t * 8);
    f4 m1v = *(const f4*)(mrow + t * 8 + 4);
    #pragma unroll
    for (int e = 0; e < 4; ++e) {
      mk[t * 8 + e] = m0v[e] * LOG2E;
      mk[t * 8 + 4 + e] = m1v[e] * LOG2E;
    }
  }

  // Q fragments for both subtiles (q = qw + lm and qw + 16 + lm), pre-scaled
  const unsigned short* qrow = qb + ((long)bh * SS + qw + lm) * HD;
  const s8v qa0 = *(const s8v*)(qrow + qd * 8);
  const s8v qa1 = *(const s8v*)(qrow + 32 + qd * 8);
  const s8v qb0 = *(const s8v*)(qrow + 16 * HD + qd * 8);
  const s8v qb1 = *(const s8v*)(qrow + 16 * HD + 32 + qd * 8);

  // Fused qrel: qr2[dist][q_local] = q_scaled . table[dist], both subtiles
  #pragma unroll
  for (int cb = 0; cb < 9; ++cb) {
    int dist = cb * 16 + lm;
    int dc = dist > NREL - 1 ? NREL - 1 : dist;
    const float* trow = tableF + dc * HD;
    f4 t0 = *(const f4*)(trow + qd * 8);
    f4 t1 = *(const f4*)(trow + qd * 8 + 4);
    f4 t2 = *(const f4*)(trow + 32 + qd * 8);
    f4 t3 = *(const f4*)(trow + 32 + qd * 8 + 4);
    unsigned int tb[8];
    tb[0] = pk2bf(t0[0], t0[1]); tb[1] = pk2bf(t0[2], t0[3]);
    tb[2] = pk2bf(t1[0], t1[1]); tb[3] = pk2bf(t1[2], t1[3]);
    tb[4] = pk2bf(t2[0], t2[1]); tb[5] = pk2bf(t2[2], t2[3]);
    tb[6] = pk2bf(t3[0], t3[1]); tb[7] = pk2bf(t3[2], t3[3]);
    s8v b0 = *(s8v*)tb, b1 = *(s8v*)(tb + 4);
    f4 c0 = MFMA_BF16(qa0, b0, (f4)0.0f, 0, 0, 0);
    c0 = MFMA_BF16(qa1, b1, c0, 0, 0, 0);
    f4 c1 = MFMA_BF16(qb0, b0, (f4)0.0f, 0, 0, 0);
    c1 = MFMA_BF16(qb1, b1, c1, 0, 0, 0);
    if (dist <= NREL - 1) {
      #pragma unroll
      for (int r = 0; r < 4; ++r) {
        qr2[dist][w * 32 + qd * 4 + r] = f2bf(c0[r]);
        qr2[dist][w * 32 + 16 + qd * 4 + r] = f2bf(c1[r]);
      }
    }
  }
  __syncthreads();   // qr2 + mk visible block-wide; ONLY barrier in kernel

  const float bLo0 = bf2f(qr2[0][qc0]), bHi0 = bf2f(qr2[128][qc0]);
  const float bLo1 = bf2f(qr2[0][qc1]), bHi1 = bf2f(qr2[128][qc1]);

  float m0_ = -1e30f, l0_ = 0.0f, m1_ = -1e30f, l1_ = 0.0f;
  f4 c40[4], c41[4];
  #pragma unroll
  for (int i = 0; i < 4; ++i) { c40[i] = (f4)0.0f; c41[i] = (f4)0.0f; }

  // main loop: even/odd bodies swap the K/V register buffers (static names)
  for (int rp = 0; rp < 16; ++rp) {
    ATTN_STEP(2 * rp, K0, V0, K1, V1, true);
    ATTN_STEP(2 * rp + 1, K1, V1, K0, V0, (rp < 15));
  }

  const float inv0 = 1.0f / l0_, inv1 = 1.0f / l1_;
  float* ob0 = out + ((long)b * SS + q0 + qc0) * DD + h * HD;
  float* ob1 = out + ((long)b * SS + q0 + qc1) * DD + h * HD;
  #pragma unroll
  for (int db = 0; db < 4; ++db) {
    f4 o0, o1;
    #pragma unroll
    for (int r = 0; r < 4; ++r) {
      o0[r] = c40[db][r] * inv0;
      o1[r] = c41[db][r] * inv1;
    }
    *(f4*)(ob0 + db * 16 + qd * 4) = o0;
    *(f4*)(ob1 + db * 16 + qd * 4) = o1;
  }
}

// ---------------------------------------------------------------------------
extern "C" void kernel_launch(void* const* d_in, const int* in_sizes, int n_in,
                              void* d_out, int out_size, void* d_ws, size_t ws_size,
                              hipStream_t stream) {
  const float* query = (const float*)d_in[0];
  const float* key   = (const float*)d_in[1];
  const float* value = (const float*)d_in[2];
  const float* mask  = (const float*)d_in[3];
  const float* Wq    = (const float*)d_in[4];
  const float* bq    = (const float*)d_in[5];
  const float* Wk    = (const float*)d_in[6];
  const float* bk    = (const float*)d_in[7];
  const float* Wv    = (const float*)d_in[8];
  const float* bv    = (const float*)d_in[9];
  const float* table = (const float*)d_in[10];

  char* ws = (char*)d_ws;
  // workspace layout (bytes), span 56 MB
  unsigned short* WTt   = (unsigned short*)(ws);               // 6,291,456 (tiled)
  unsigned short* Xb    = (unsigned short*)(ws + (8l << 20));  // 25,165,824
  unsigned short* qbuf  = (unsigned short*)(ws + (32l << 20));
  unsigned short* ktile = (unsigned short*)(ws + (40l << 20));
  unsigned short* vtile = (unsigned short*)(ws + (48l << 20));

  // 1) convert inputs fp32 -> bf16 (once)
  cvt_x<<<dim3(2048, 3, 1), 256, 0, stream>>>(query, key, value, Xb);

  // 2) transpose+convert weights into proj's tiled LDS image
  cvt_w<<<dim3(16, 16, 3), 256, 0, stream>>>(Wq, Wk, Wv, WTt);

  // 3) fused QKV projections; K/V written as attn's register-tiled images
  proj_gemm<<<dim3(8, 32, 3), 256, 0, stream>>>(Xb, WTt, bq, bk, bv,
                                                qbuf, ktile, vtile);

  // 4) flash attention: barrier-free main loop, K/V reg-double-buffered
  //    from L2 (per-bh K/V = 512 KB, L2-resident; 4 waves share via L1)
  attn<<<dim3(16, 32, 1), 256, 0, stream>>>(qbuf, ktile, vtile, table, mask,
                                            (float*)d_out);
}

// Round 7
// 232.882 us; speedup vs baseline: 1.4964x; 1.4964x over previous
//
#include <hip/hip_runtime.h>
#include <hip/hip_bf16.h>

// Problem constants
#define BB 2
#define SS 2048
#define DD 1024
#define HH 16
#define HD 64
#define NREL 129
#define LOG2E 1.4426950408889634f
#define SCALEQ (LOG2E / 8.0f)   // folded into Q at projection time
#define KVB 131072l              // elems per bh in ktile/vtile (32*8*64*8)

typedef short s8v __attribute__((ext_vector_type(8)));
typedef short s4v __attribute__((ext_vector_type(4)));
typedef float f4 __attribute__((ext_vector_type(4)));

#define MFMA_BF16 __builtin_amdgcn_mfma_f32_16x16x32_bf16

__device__ __forceinline__ float bf2f(unsigned short u) {
  union { unsigned int i; float f; } x; x.i = ((unsigned int)u) << 16; return x.f;
}
__device__ __forceinline__ unsigned short f2bf(float f) {
  union { float f; unsigned int i; } x; x.f = f;
  unsigned int r = x.i + 0x7fffu + ((x.i >> 16) & 1u);
  return (unsigned short)(r >> 16);
}
__device__ __forceinline__ unsigned int pk2bf(float a, float b) {
  union { __hip_bfloat162 h2; unsigned int u; } c;
  c.h2 = __float22bfloat162_rn(float2{a, b});
  return c.u;
}
// async global->LDS DMA, 16B/lane; global src MUST be lane-contiguous for
// coalescing (tiled layouts below guarantee it); LDS dest = base + lane*16
__device__ __forceinline__ void gl_lds16(const void* g, void* l) {
  __builtin_amdgcn_global_load_lds(
      (const __attribute__((address_space(1))) unsigned int*)g,
      (__attribute__((address_space(3))) unsigned int*)l, 16, 0, 0);
}

// ---------------------------------------------------------------------------
// fp32 -> bf16 convert of the 3 input tensors [4096][1024] -> xb [3][4096*1024]
// Also pre-scales the additive mask by LOG2E into mkg[2][2048] (f32).
__global__ __launch_bounds__(256) void cvt_x(
    const float* __restrict__ xq, const float* __restrict__ xk,
    const float* __restrict__ xv, const float* __restrict__ mask,
    unsigned short* __restrict__ xb, float* __restrict__ mkg) {
  const int z = blockIdx.y;
  const float* in = (z == 0) ? xq : (z == 1) ? xk : xv;
  unsigned short* out = xb + (long)z * 4096 * DD;
  const long i = ((long)blockIdx.x * 256 + threadIdx.x) * 8;
  f4 a = *(const f4*)(in + i);
  f4 b = *(const f4*)(in + i + 4);
  unsigned int u[4];
  u[0] = pk2bf(a[0], a[1]); u[1] = pk2bf(a[2], a[3]);
  u[2] = pk2bf(b[0], b[1]); u[3] = pk2bf(b[2], b[3]);
  *(s8v*)(out + i) = *(s8v*)u;
  if (z == 0 && blockIdx.x < BB) {
    const int row = blockIdx.x;
    const long j = (long)row * SS + threadIdx.x * 8;
    f4 ma = *(const f4*)(mask + j);
    f4 mb = *(const f4*)(mask + j + 4);
    #pragma unroll
    for (int e = 0; e < 4; ++e) {
      mkg[j + e] = ma[e] * LOG2E;
      mkg[j + 4 + e] = mb[e] * LOG2E;
    }
  }
}

// ---------------------------------------------------------------------------
// Weight transpose+convert to TILED layout:
// WTt[z][n0g(8)][k0g(16)][kc(8)][n(128)][8k] — 16 KB per (n0,k0) tile,
// byte-image of proj_gemm's LDS tile. grid (16, 16, 3), block 256.
__global__ __launch_bounds__(256) void cvt_w(
    const float* __restrict__ Wq, const float* __restrict__ Wk,
    const float* __restrict__ Wv, unsigned short* __restrict__ WTt) {
  __shared__ unsigned short tile[64][72];
  const int z = blockIdx.z;
  const float* in = (z == 0) ? Wq : (z == 1) ? Wk : Wv;
  unsigned short* out = WTt + (long)z * 1048576;
  const int c0 = blockIdx.x * 64, r0 = blockIdx.y * 64;  // c0: n-base, r0: k-base
  const int t = threadIdx.x;
  const int r = t >> 2;
  #pragma unroll
  for (int j = 0; j < 4; ++j) {
    int cc = (t & 3) * 16 + j * 4;
    f4 v = *(const f4*)(in + (long)(r0 + r) * DD + c0 + cc);
    #pragma unroll
    for (int e = 0; e < 4; ++e) tile[r][cc + e] = f2bf(v[e]);
  }
  __syncthreads();
  const int c = t >> 2;           // n within 64-tile
  #pragma unroll
  for (int h = 0; h < 2; ++h) {
    int r8 = (t & 3) + 4 * h;     // k-octet within 64-tile
    unsigned short vals[8];
    #pragma unroll
    for (int j = 0; j < 8; ++j) vals[j] = tile[r8 * 8 + j][c];
    int n = c0 + c, kb = r0 + r8 * 8;
    long off = ((long)(n >> 7) * 131072) + ((kb >> 6) * 8192) +
               (((kb & 63) >> 3) * 1024) + ((n & 127) * 8);
    *(s8v*)(out + off) = *(s8v*)vals;
  }
}

// ---------------------------------------------------------------------------
// Fused QKV projection GEMM: C = Xb @ W + bias.
// Q head-split [bh][s][d] (pre-scaled); K -> ktile[bh][g][c][key][8];
// V -> vtile[bh][g][c][d][8]. grid (8 n, 32 m, 3 z), block 256.
__global__ __launch_bounds__(256, 4) void proj_gemm(
    const unsigned short* __restrict__ Xb, const unsigned short* __restrict__ WTt,
    const float* __restrict__ bq, const float* __restrict__ bk,
    const float* __restrict__ bv,
    unsigned short* __restrict__ qbuf, unsigned short* __restrict__ ktile,
    unsigned short* __restrict__ vtile) {
  __shared__ __align__(16) unsigned short wt[8][128][8];  // [kc][n][8k] 16KB
  unsigned short* wtf = &wt[0][0][0];
  const int z = blockIdx.z;
  const unsigned short* X = Xb + (long)z * 4096 * DD;
  const unsigned short* WTz = WTt + (long)z * 1048576;
  const float* bias = (z == 0) ? bq : (z == 1) ? bk : bv;

  const int n0 = blockIdx.x * 128, m0 = blockIdx.y * 128;
  const int t = threadIdx.x, w = t >> 6, l = t & 63;
  const int lm = l & 15, qd = l >> 4;

  f4 acc[8][2];
  #pragma unroll
  for (int i = 0; i < 8; ++i) { acc[i][0] = (f4)0.0f; acc[i][1] = (f4)0.0f; }

  const unsigned short* x0 = X + (long)(m0 + w * 32 + lm) * DD;
  const unsigned short* x1 = x0 + 16 * DD;
  const unsigned short* wtile0 = WTz + (long)(n0 >> 7) * 131072;

  for (int k0 = 0; k0 < DD; k0 += 64) {
    __syncthreads();   // all waves done reading wt from previous iter
    // stage 16 KB WT tile: 16 lane-contiguous 1KB DMA bursts
    const unsigned short* tb = wtile0 + (k0 >> 6) * 8192;
    #pragma unroll
    for (int i = 0; i < 4; ++i) {
      int idx = w * 4 + i;
      gl_lds16(tb + idx * 512 + l * 8, wtf + idx * 512);
    }
    // A fragments direct from bf16 global (L2-served)
    s8v a00 = *(const s8v*)(x0 + k0 + qd * 8);
    s8v a01 = *(const s8v*)(x0 + k0 + 32 + qd * 8);
    s8v a10 = *(const s8v*)(x1 + k0 + qd * 8);
    s8v a11 = *(const s8v*)(x1 + k0 + 32 + qd * 8);
    asm volatile("s_waitcnt vmcnt(0)" ::: "memory");
    __syncthreads();   // DMA landed for all waves
    #pragma unroll
    for (int cb = 0; cb < 8; ++cb) {
      s8v b0 = *(const s8v*)&wt[qd][cb * 16 + lm][0];
      s8v b1 = *(const s8v*)&wt[4 + qd][cb * 16 + lm][0];
      acc[cb][0] = MFMA_BF16(a00, b0, acc[cb][0], 0, 0, 0);
      acc[cb][0] = MFMA_BF16(a01, b1, acc[cb][0], 0, 0, 0);
      acc[cb][1] = MFMA_BF16(a10, b0, acc[cb][1], 0, 0, 0);
      acc[cb][1] = MFMA_BF16(a11, b1, acc[cb][1], 0, 0, 0);
    }
  }
  if (z == 0) {
    // Q: head-split [bh][s][d], pre-scaled
    #pragma unroll
    for (int cb = 0; cb < 8; ++cb) {
      int n = n0 + cb * 16 + lm;
      float bvv = bias[n];
      int hh = n >> 6, d = n & 63;
      #pragma unroll
      for (int ms = 0; ms < 2; ++ms) {
        #pragma unroll
        for (int r = 0; r < 4; ++r) {
          int m = m0 + w * 32 + ms * 16 + qd * 4 + r;
          int bidx = m >> 11, s = m & (SS - 1);
          qbuf[((long)(bidx * HH + hh) * SS + s) * HD + d] =
              f2bf((acc[cb][ms][r] + bvv) * SCALEQ);
        }
      }
    }
  } else if (z == 1) {
    // K -> ktile[bh][g][c][key][8]
    #pragma unroll
    for (int cb = 0; cb < 8; ++cb) {
      int n = n0 + cb * 16 + lm;
      float bvv = bias[n];
      int hh = n >> 6, d = n & 63;
      int c = d >> 3, e = d & 7;
      #pragma unroll
      for (int ms = 0; ms < 2; ++ms) {
        #pragma unroll
        for (int r = 0; r < 4; ++r) {
          int m = m0 + w * 32 + ms * 16 + qd * 4 + r;
          int bidx = m >> 11, s = m & (SS - 1);
          long bh = bidx * HH + hh;
          ktile[bh * KVB + (s >> 6) * 4096 + c * 512 + (s & 63) * 8 + e] =
              f2bf(acc[cb][ms][r] + bvv);
        }
      }
    }
  } else {
    // V -> vtile[bh][g][c][d][8], 4 consecutive s per 8B store
    #pragma unroll
    for (int cb = 0; cb < 8; ++cb) {
      int n = n0 + cb * 16 + lm;
      float bvv = bias[n];
      int hh = n >> 6, d = n & 63;
      #pragma unroll
      for (int ms = 0; ms < 2; ++ms) {
        int m = m0 + w * 32 + ms * 16 + qd * 4;
        int bidx = m >> 11, s = m & (SS - 1);
        long bh = bidx * HH + hh;
        unsigned short o4[4];
        #pragma unroll
        for (int r = 0; r < 4; ++r) o4[r] = f2bf(acc[cb][ms][r] + bvv);
        *(s4v*)&vtile[bh * KVB + (s >> 6) * 4096 + ((s & 63) >> 3) * 512 +
                      d * 8 + (s & 7)] = *(s4v*)o4;
      }
    }
  }
}

// ---------------------------------------------------------------------------
// Flash attention (round-3 structure + 3 verified refinements):
//  - merged pbuf rounds: two per-wave P buffers (pb0/pb1), ONE lgkmcnt drain
//    serves both subtiles -> 2 drains/iter instead of 4 (round-6-verified).
//  - mask from global/L1 (pre-scaled by cvt_x) instead of LDS: removes LDS
//    reads from the z-path and pays the +5KB for pb1 (block = 76.5 KB,
//    2 blocks/CU preserved: 153 KB < 160 KB).
//  - defer-max (T13, THR=8 in log2 domain): skip alpha/rescale when
//    __all(tm - m <= 8); wave-uniform branch; exact refactorization.
// K/V LDS-staged via gl_lds16 double-buffer (round-3-proven).
// grid (16 q-blocks, 32 bh), block 256. launch_bounds(256,2): natural VGPR.
__global__ __launch_bounds__(256, 2) void attn(
    const unsigned short* __restrict__ qb, const unsigned short* __restrict__ ktile,
    const unsigned short* __restrict__ vtile, const float* __restrict__ tableF,
    const float* __restrict__ mkg, float* __restrict__ out) {
  __shared__ __align__(16) unsigned short ks[2][8][64][8];  // [buf][d-chunk][key][8d]
  __shared__ __align__(16) unsigned short vs[2][8][64][8];  // [buf][k-chunk][d][8k]
  __shared__ __align__(16) unsigned short qr2[NREL][130];   // [dist][q_local+pad]
  __shared__ __align__(16) unsigned short pb0[4][16][40];   // per-wave P, sub0
  __shared__ __align__(16) unsigned short pb1[4][16][40];   // per-wave P, sub1

  const int bh = blockIdx.y, b = bh >> 4, h = bh & 15;
  const int q0 = blockIdx.x * 128;
  const int t = threadIdx.x, w = t >> 6, l = t & 63;
  const int lm = l & 15, qd = l >> 4;
  const int qw = q0 + w * 32;          // this wave's q base (32 rows)
  const int qc0 = w * 32 + lm, qc1 = qc0 + 16;  // local q cols of the 2 subtiles

  const unsigned short* kkb = ktile + (long)bh * KVB;
  const unsigned short* vvb = vtile + (long)bh * KVB;

  // stage round 0 (key-group 0) into buf 0: lane-contiguous 1KB bursts
  #pragma unroll
  for (int i = 0; i < 2; ++i) {
    int c = 2 * w + i;
    gl_lds16(kkb + c * 512 + l * 8, &ks[0][c][0][0]);
    gl_lds16(vvb + c * 512 + l * 8, &vs[0][c][0][0]);
  }

  // Q fragments for both subtiles (q = qw + lm and qw + 16 + lm), pre-scaled
  const unsigned short* qrow = qb + ((long)bh * SS + qw + lm) * HD;
  const s8v qa0 = *(const s8v*)(qrow + qd * 8);
  const s8v qa1 = *(const s8v*)(qrow + 32 + qd * 8);
  const s8v qb0 = *(const s8v*)(qrow + 16 * HD + qd * 8);
  const s8v qb1 = *(const s8v*)(qrow + 16 * HD + 32 + qd * 8);

  // Fused qrel: qr2[dist][q_local] = q_scaled . table[dist], both subtiles
  #pragma unroll
  for (int cb = 0; cb < 9; ++cb) {
    int dist = cb * 16 + lm;
    int dc = dist > NREL - 1 ? NREL - 1 : dist;
    const float* trow = tableF + dc * HD;
    f4 t0 = *(const f4*)(trow + qd * 8);
    f4 t1 = *(const f4*)(trow + qd * 8 + 4);
    f4 t2 = *(const f4*)(trow + 32 + qd * 8);
    f4 t3 = *(const f4*)(trow + 32 + qd * 8 + 4);
    unsigned int tb[8];
    tb[0] = pk2bf(t0[0], t0[1]); tb[1] = pk2bf(t0[2], t0[3]);
    tb[2] = pk2bf(t1[0], t1[1]); tb[3] = pk2bf(t1[2], t1[3]);
    tb[4] = pk2bf(t2[0], t2[1]); tb[5] = pk2bf(t2[2], t2[3]);
    tb[6] = pk2bf(t3[0], t3[1]); tb[7] = pk2bf(t3[2], t3[3]);
    s8v b0 = *(s8v*)tb, b1 = *(s8v*)(tb + 4);
    f4 c0 = MFMA_BF16(qa0, b0, (f4)0.0f, 0, 0, 0);
    c0 = MFMA_BF16(qa1, b1, c0, 0, 0, 0);
    f4 c1 = MFMA_BF16(qb0, b0, (f4)0.0f, 0, 0, 0);
    c1 = MFMA_BF16(qb1, b1, c1, 0, 0, 0);
    if (dist <= NREL - 1) {
      #pragma unroll
      for (int r = 0; r < 4; ++r) {
        qr2[dist][w * 32 + qd * 4 + r] = f2bf(c0[r]);
        qr2[dist][w * 32 + 16 + qd * 4 + r] = f2bf(c1[r]);
      }
    }
  }
  asm volatile("s_waitcnt vmcnt(0)" ::: "memory");
  __syncthreads();

  const float bLo0 = bf2f(qr2[0][qc0]), bHi0 = bf2f(qr2[128][qc0]);
  const float bLo1 = bf2f(qr2[0][qc1]), bHi1 = bf2f(qr2[128][qc1]);
  const float* mrow = mkg + b * SS;               // mask*LOG2E (L1-resident)

  float m0_ = -1e30f, l0_ = 0.0f, m1_ = -1e30f, l1_ = 0.0f;
  f4 c40[4], c41[4];
  #pragma unroll
  for (int i = 0; i < 4; ++i) { c40[i] = (f4)0.0f; c41[i] = (f4)0.0f; }

  for (int rr = 0; rr < 32; ++rr) {
    const int kk = rr << 6;
    const int buf = rr & 1;
    if (rr < 31) {
      const int nb = buf ^ 1;
      const unsigned short* kg = kkb + (rr + 1) * 4096;
      const unsigned short* vg = vvb + (rr + 1) * 4096;
      #pragma unroll
      for (int i = 0; i < 2; ++i) {
        int c = 2 * w + i;
        gl_lds16(kg + c * 512 + l * 8, &ks[nb][c][0][0]);
        gl_lds16(vg + c * 512 + l * 8, &vs[nb][c][0][0]);
      }
    }
    // QK^T for both subtiles: K fragments read once, used twice
    f4 st0[4], st1[4];
    #pragma unroll
    for (int tt = 0; tt < 4; ++tt) {
      s8v k0v = *(const s8v*)&ks[buf][qd][tt * 16 + lm][0];
      s8v k1v = *(const s8v*)&ks[buf][4 + qd][tt * 16 + lm][0];
      st0[tt] = MFMA_BF16(k0v, qa0, (f4)0.0f, 0, 0, 0);
      st0[tt] = MFMA_BF16(k1v, qa1, st0[tt], 0, 0, 0);
      st1[tt] = MFMA_BF16(k0v, qb0, (f4)0.0f, 0, 0, 0);
      st1[tt] = MFMA_BF16(k1v, qb1, st1[tt], 0, 0, 0);
    }
    float z0[16], z1[16];
    const int kw = kk - qw;  // key-band offset relative to this wave's q range
    if (kw >= 96) {          // all dist >= 65 for this wave's 32 q
      #pragma unroll
      for (int tt = 0; tt < 4; ++tt) {
        f4 mv = *(const f4*)&mrow[kk + tt * 16 + qd * 4];
        #pragma unroll
        for (int r = 0; r < 4; ++r) {
          z0[tt * 4 + r] = st0[tt][r] + bHi0 + mv[r];
          z1[tt * 4 + r] = st1[tt][r] + bHi1 + mv[r];
        }
      }
    } else if (kw <= -128) { // all dist <= -65
      #pragma unroll
      for (int tt = 0; tt < 4; ++tt) {
        f4 mv = *(const f4*)&mrow[kk + tt * 16 + qd * 4];
        #pragma unroll
        for (int r = 0; r < 4; ++r) {
          z0[tt * 4 + r] = st0[tt][r] + bLo0 + mv[r];
          z1[tt * 4 + r] = st1[tt][r] + bLo1 + mv[r];
        }
      }
    } else {                 // diagonal band (3 iters/wave): LDS qrel lookups
      const int db0 = kw - lm + 64 + qd * 4;
      #pragma unroll
      for (int tt = 0; tt < 4; ++tt) {
        f4 mv = *(const f4*)&mrow[kk + tt * 16 + qd * 4];
        #pragma unroll
        for (int r = 0; r < 4; ++r) {
          int du = db0 + tt * 16 + r;
          int d0 = du < 0 ? 0 : (du > 128 ? 128 : du);
          int d1 = du - 16; d1 = d1 < 0 ? 0 : (d1 > 128 ? 128 : d1);
          z0[tt * 4 + r] = st0[tt][r] + bf2f(qr2[d0][qc0]) + mv[r];
          z1[tt * 4 + r] = st1[tt][r] + bf2f(qr2[d1][qc1]) + mv[r];
        }
      }
    }
    // online softmax with defer-max (T13): rescale only when max grew > 8
    float tm0 = z0[0], tm1 = z1[0];
    #pragma unroll
    for (int i = 1; i < 16; ++i) {
      tm0 = fmaxf(tm0, z0[i]);
      tm1 = fmaxf(tm1, z1[i]);
    }
    tm0 = fmaxf(tm0, __shfl_xor(tm0, 16));
    tm0 = fmaxf(tm0, __shfl_xor(tm0, 32));
    tm1 = fmaxf(tm1, __shfl_xor(tm1, 16));
    tm1 = fmaxf(tm1, __shfl_xor(tm1, 32));
    if (!__all(tm0 - m0_ <= 8.0f)) {
      float mn0 = fmaxf(m0_, tm0);
      float al0 = __builtin_amdgcn_exp2f(m0_ - mn0);
      m0_ = mn0; l0_ *= al0;
      #pragma unroll
      for (int db = 0; db < 4; ++db)
        #pragma unroll
        for (int r = 0; r < 4; ++r) c40[db][r] *= al0;
    }
    if (!__all(tm1 - m1_ <= 8.0f)) {
      float mn1 = fmaxf(m1_, tm1);
      float al1 = __builtin_amdgcn_exp2f(m1_ - mn1);
      m1_ = mn1; l1_ *= al1;
      #pragma unroll
      for (int db = 0; db < 4; ++db)
        #pragma unroll
        for (int r = 0; r < 4; ++r) c41[db][r] *= al1;
    }
    float s0 = 0.0f, s1 = 0.0f;
    #pragma unroll
    for (int i = 0; i < 16; ++i) {
      z0[i] = __builtin_amdgcn_exp2f(z0[i] - m0_); s0 += z0[i];
      z1[i] = __builtin_amdgcn_exp2f(z1[i] - m1_); s1 += z1[i];
    }
    s0 += __shfl_xor(s0, 16);
    s0 += __shfl_xor(s0, 32);
    s1 += __shfl_xor(s1, 16);
    s1 += __shfl_xor(s1, 32);
    l0_ += s0; l1_ += s1;

    // PV phase A (keys 0..31): merged round — one drain for both subtiles
    {
      *(unsigned int*)&pb0[w][lm][qd * 4]          = pk2bf(z0[0], z0[1]);
      *(unsigned int*)&pb0[w][lm][qd * 4 + 2]      = pk2bf(z0[2], z0[3]);
      *(unsigned int*)&pb0[w][lm][16 + qd * 4]     = pk2bf(z0[4], z0[5]);
      *(unsigned int*)&pb0[w][lm][16 + qd * 4 + 2] = pk2bf(z0[6], z0[7]);
      *(unsigned int*)&pb1[w][lm][qd * 4]          = pk2bf(z1[0], z1[1]);
      *(unsigned int*)&pb1[w][lm][qd * 4 + 2]      = pk2bf(z1[2], z1[3]);
      *(unsigned int*)&pb1[w][lm][16 + qd * 4]     = pk2bf(z1[4], z1[5]);
      *(unsigned int*)&pb1[w][lm][16 + qd * 4 + 2] = pk2bf(z1[6], z1[7]);
      asm volatile("s_waitcnt lgkmcnt(0)" ::: "memory");
      s8v pa0 = *(const s8v*)&pb0[w][lm][qd * 8];
      s8v pa1 = *(const s8v*)&pb1[w][lm][qd * 8];
      #pragma unroll
      for (int db = 0; db < 4; ++db) {
        s8v va = *(const s8v*)&vs[buf][qd][db * 16 + lm][0];
        c40[db] = MFMA_BF16(va, pa0, c40[db], 0, 0, 0);
        c41[db] = MFMA_BF16(va, pa1, c41[db], 0, 0, 0);
      }
    }
    // PV phase B (keys 32..63); same-wave DS ordering makes overwrite safe
    {
      *(unsigned int*)&pb0[w][lm][qd * 4]          = pk2bf(z0[8], z0[9]);
      *(unsigned int*)&pb0[w][lm][qd * 4 + 2]      = pk2bf(z0[10], z0[11]);
      *(unsigned int*)&pb0[w][lm][16 + qd * 4]     = pk2bf(z0[12], z0[13]);
      *(unsigned int*)&pb0[w][lm][16 + qd * 4 + 2] = pk2bf(z0[14], z0[15]);
      *(unsigned int*)&pb1[w][lm][qd * 4]          = pk2bf(z1[8], z1[9]);
      *(unsigned int*)&pb1[w][lm][qd * 4 + 2]      = pk2bf(z1[10], z1[11]);
      *(unsigned int*)&pb1[w][lm][16 + qd * 4]     = pk2bf(z1[12], z1[13]);
      *(unsigned int*)&pb1[w][lm][16 + qd * 4 + 2] = pk2bf(z1[14], z1[15]);
      asm volatile("s_waitcnt lgkmcnt(0)" ::: "memory");
      s8v pB0 = *(const s8v*)&pb0[w][lm][qd * 8];
      s8v pB1 = *(const s8v*)&pb1[w][lm][qd * 8];
      #pragma unroll
      for (int db = 0; db < 4; ++db) {
        s8v vb = *(const s8v*)&vs[buf][4 + qd][db * 16 + lm][0];
        c40[db] = MFMA_BF16(vb, pB0, c40[db], 0, 0, 0);
        c41[db] = MFMA_BF16(vb, pB1, c41[db], 0, 0, 0);
      }
    }
    asm volatile("s_waitcnt vmcnt(0)" ::: "memory");
    __syncthreads();
  }

  const float inv0 = 1.0f / l0_, inv1 = 1.0f / l1_;
  float* ob0 = out + ((long)b * SS + q0 + qc0) * DD + h * HD;
  float* ob1 = out + ((long)b * SS + q0 + qc1) * DD + h * HD;
  #pragma unroll
  for (int db = 0; db < 4; ++db) {
    f4 o0, o1;
    #pragma unroll
    for (int r = 0; r < 4; ++r) {
      o0[r] = c40[db][r] * inv0;
      o1[r] = c41[db][r] * inv1;
    }
    *(f4*)(ob0 + db * 16 + qd * 4) = o0;
    *(f4*)(ob1 + db * 16 + qd * 4) = o1;
  }
}

// ---------------------------------------------------------------------------
extern "C" void kernel_launch(void* const* d_in, const int* in_sizes, int n_in,
                              void* d_out, int out_size, void* d_ws, size_t ws_size,
                              hipStream_t stream) {
  const float* query = (const float*)d_in[0];
  const float* key   = (const float*)d_in[1];
  const float* value = (const float*)d_in[2];
  const float* mask  = (const float*)d_in[3];
  const float* Wq    = (const float*)d_in[4];
  const float* bq    = (const float*)d_in[5];
  const float* Wk    = (const float*)d_in[6];
  const float* bk    = (const float*)d_in[7];
  const float* Wv    = (const float*)d_in[8];
  const float* bv    = (const float*)d_in[9];
  const float* table = (const float*)d_in[10];

  char* ws = (char*)d_ws;
  // workspace layout (bytes), span 56 MB
  unsigned short* WTt   = (unsigned short*)(ws);               // 6,291,456 (tiled)
  float*          mkg   = (float*)(ws + (7l << 20));           // 16 KB mask*LOG2E
  unsigned short* Xb    = (unsigned short*)(ws + (8l << 20));  // 25,165,824
  unsigned short* qbuf  = (unsigned short*)(ws + (32l << 20));
  unsigned short* ktile = (unsigned short*)(ws + (40l << 20));
  unsigned short* vtile = (unsigned short*)(ws + (48l << 20));

  // 1) convert inputs fp32 -> bf16 (once); pre-scale mask
  cvt_x<<<dim3(2048, 3, 1), 256, 0, stream>>>(query, key, value, mask, Xb, mkg);

  // 2) transpose+convert weights into proj's tiled LDS image
  cvt_w<<<dim3(16, 16, 3), 256, 0, stream>>>(Wq, Wk, Wv, WTt);

  // 3) fused QKV projections; K/V written as attn's tiled LDS images
  proj_gemm<<<dim3(8, 32, 3), 256, 0, stream>>>(Xb, WTt, bq, bk, bv,
                                                qbuf, ktile, vtile);

  // 4) flash attention: round-3 base + merged pbuf + L1 mask + defer-max
  attn<<<dim3(16, 32, 1), 256, 0, stream>>>(qbuf, ktile, vtile, table,
                                            mkg, (float*)d_out);
}

// Round 8
// 228.436 us; speedup vs baseline: 1.5255x; 1.0195x over previous
//
#include <hip/hip_runtime.h>
#include <hip/hip_bf16.h>

// Problem constants
#define BB 2
#define SS 2048
#define DD 1024
#define HH 16
#define HD 64
#define NREL 129
#define LOG2E 1.4426950408889634f
#define SCALEQ (LOG2E / 8.0f)   // folded into Q at projection time
#define KVB 131072l              // elems per bh in ktile/vtile (32*8*64*8)

typedef short s8v __attribute__((ext_vector_type(8)));
typedef short s4v __attribute__((ext_vector_type(4)));
typedef float f4 __attribute__((ext_vector_type(4)));
typedef unsigned int u32x2 __attribute__((ext_vector_type(2)));

#define MFMA_BF16 __builtin_amdgcn_mfma_f32_16x16x32_bf16

__device__ __forceinline__ float bf2f(unsigned short u) {
  union { unsigned int i; float f; } x; x.i = ((unsigned int)u) << 16; return x.f;
}
__device__ __forceinline__ unsigned short f2bf(float f) {
  union { float f; unsigned int i; } x; x.f = f;
  unsigned int r = x.i + 0x7fffu + ((x.i >> 16) & 1u);
  return (unsigned short)(r >> 16);
}
__device__ __forceinline__ unsigned int pk2bf(float a, float b) {
  union { __hip_bfloat162 h2; unsigned int u; } c;
  c.h2 = __float22bfloat162_rn(float2{a, b});
  return c.u;
}
// async global->LDS DMA, 16B/lane; global src MUST be lane-contiguous for
// coalescing (tiled layouts below guarantee it); LDS dest = base + lane*16
__device__ __forceinline__ void gl_lds16(const void* g, void* l) {
  __builtin_amdgcn_global_load_lds(
      (const __attribute__((address_space(1))) unsigned int*)g,
      (__attribute__((address_space(3))) unsigned int*)l, 16, 0, 0);
}

// ---- gfx950 16-lane-row swaps (P transpose, in-register) ------------------
// permlane32_swap(a,b): a'=[a0,a1,b0,b1], b'=[a2,a3,b2,b3]  (rows = 16 lanes)
// permlane16_swap(a,b): a'=[a0,b0,a2,b2], b'=[a1,b1,a3,b3]
// NOTE: operands MUST be distinct values (the instruction swaps both
// registers in place; same-register calls self-swap — round-1 bug).
__device__ __forceinline__ u32x2 pl32(unsigned a, unsigned b) {
  return __builtin_amdgcn_permlane32_swap(a, b, false, false);
}
__device__ __forceinline__ u32x2 pl16(unsigned a, unsigned b) {
  return __builtin_amdgcn_permlane16_swap(a, b, false, false);
}
// Build the PV B-operand fragment from 8 per-lane P values.
// Source lane (g,lm): p[i] = P[key = (i>>2)*16 + g*4 + (i&3)][q=lm].
// Dest lane (g,lm) must hold keys g*8..g*8+7 (B layout proven by the
// pbuf path: lane reads pbuf[q=lm][qd*8 + j]).
// w0 = pl16(pl32(pk01,pk45))[0], w2 = [1]; w1/w3 from (pk23,pk67).
__device__ __forceinline__ s8v mkfrag(float p0, float p1, float p2, float p3,
                                      float p4, float p5, float p6, float p7) {
  u32x2 sa = pl32(pk2bf(p0, p1), pk2bf(p4, p5));
  u32x2 ta = pl16(sa[0], sa[1]);
  u32x2 sb = pl32(pk2bf(p2, p3), pk2bf(p6, p7));
  u32x2 tb = pl16(sb[0], sb[1]);
  unsigned fr[4] = {ta[0], tb[0], ta[1], tb[1]};
  return *(s8v*)fr;
}

// ---------------------------------------------------------------------------
// fp32 -> bf16 convert of the 3 input tensors [4096][1024] -> xb [3][4096*1024]
// Also pre-scales the additive mask by LOG2E into mkg[2][2048] (f32).
__global__ __launch_bounds__(256) void cvt_x(
    const float* __restrict__ xq, const float* __restrict__ xk,
    const float* __restrict__ xv, const float* __restrict__ mask,
    unsigned short* __restrict__ xb, float* __restrict__ mkg) {
  const int z = blockIdx.y;
  const float* in = (z == 0) ? xq : (z == 1) ? xk : xv;
  unsigned short* out = xb + (long)z * 4096 * DD;
  const long i = ((long)blockIdx.x * 256 + threadIdx.x) * 8;
  f4 a = *(const f4*)(in + i);
  f4 b = *(const f4*)(in + i + 4);
  unsigned int u[4];
  u[0] = pk2bf(a[0], a[1]); u[1] = pk2bf(a[2], a[3]);
  u[2] = pk2bf(b[0], b[1]); u[3] = pk2bf(b[2], b[3]);
  *(s8v*)(out + i) = *(s8v*)u;
  if (z == 0 && blockIdx.x < BB) {
    const int row = blockIdx.x;
    const long j = (long)row * SS + threadIdx.x * 8;
    f4 ma = *(const f4*)(mask + j);
    f4 mb = *(const f4*)(mask + j + 4);
    #pragma unroll
    for (int e = 0; e < 4; ++e) {
      mkg[j + e] = ma[e] * LOG2E;
      mkg[j + 4 + e] = mb[e] * LOG2E;
    }
  }
}

// ---------------------------------------------------------------------------
// Weight transpose+convert to TILED layout:
// WTt[z][n0g(8)][k0g(16)][kc(8)][n(128)][8k] — 16 KB per (n0,k0) tile,
// byte-image of proj_gemm's LDS tile. grid (16, 16, 3), block 256.
__global__ __launch_bounds__(256) void cvt_w(
    const float* __restrict__ Wq, const float* __restrict__ Wk,
    const float* __restrict__ Wv, unsigned short* __restrict__ WTt) {
  __shared__ unsigned short tile[64][72];
  const int z = blockIdx.z;
  const float* in = (z == 0) ? Wq : (z == 1) ? Wk : Wv;
  unsigned short* out = WTt + (long)z * 1048576;
  const int c0 = blockIdx.x * 64, r0 = blockIdx.y * 64;  // c0: n-base, r0: k-base
  const int t = threadIdx.x;
  const int r = t >> 2;
  #pragma unroll
  for (int j = 0; j < 4; ++j) {
    int cc = (t & 3) * 16 + j * 4;
    f4 v = *(const f4*)(in + (long)(r0 + r) * DD + c0 + cc);
    #pragma unroll
    for (int e = 0; e < 4; ++e) tile[r][cc + e] = f2bf(v[e]);
  }
  __syncthreads();
  const int c = t >> 2;           // n within 64-tile
  #pragma unroll
  for (int h = 0; h < 2; ++h) {
    int r8 = (t & 3) + 4 * h;     // k-octet within 64-tile
    unsigned short vals[8];
    #pragma unroll
    for (int j = 0; j < 8; ++j) vals[j] = tile[r8 * 8 + j][c];
    int n = c0 + c, kb = r0 + r8 * 8;
    long off = ((long)(n >> 7) * 131072) + ((kb >> 6) * 8192) +
               (((kb & 63) >> 3) * 1024) + ((n & 127) * 8);
    *(s8v*)(out + off) = *(s8v*)vals;
  }
}

// ---------------------------------------------------------------------------
// Fused QKV projection GEMM: C = Xb @ W + bias.
// Q head-split [bh][s][d] (pre-scaled); K -> ktile[bh][g][c][key][8];
// V -> vtile[bh][g][c][d][8]. grid (8 n, 32 m, 3 z), block 256.
__global__ __launch_bounds__(256, 4) void proj_gemm(
    const unsigned short* __restrict__ Xb, const unsigned short* __restrict__ WTt,
    const float* __restrict__ bq, const float* __restrict__ bk,
    const float* __restrict__ bv,
    unsigned short* __restrict__ qbuf, unsigned short* __restrict__ ktile,
    unsigned short* __restrict__ vtile) {
  __shared__ __align__(16) unsigned short wt[8][128][8];  // [kc][n][8k] 16KB
  unsigned short* wtf = &wt[0][0][0];
  const int z = blockIdx.z;
  const unsigned short* X = Xb + (long)z * 4096 * DD;
  const unsigned short* WTz = WTt + (long)z * 1048576;
  const float* bias = (z == 0) ? bq : (z == 1) ? bk : bv;

  const int n0 = blockIdx.x * 128, m0 = blockIdx.y * 128;
  const int t = threadIdx.x, w = t >> 6, l = t & 63;
  const int lm = l & 15, qd = l >> 4;

  f4 acc[8][2];
  #pragma unroll
  for (int i = 0; i < 8; ++i) { acc[i][0] = (f4)0.0f; acc[i][1] = (f4)0.0f; }

  const unsigned short* x0 = X + (long)(m0 + w * 32 + lm) * DD;
  const unsigned short* x1 = x0 + 16 * DD;
  const unsigned short* wtile0 = WTz + (long)(n0 >> 7) * 131072;

  for (int k0 = 0; k0 < DD; k0 += 64) {
    __syncthreads();   // all waves done reading wt from previous iter
    // stage 16 KB WT tile: 16 lane-contiguous 1KB DMA bursts
    const unsigned short* tb = wtile0 + (k0 >> 6) * 8192;
    #pragma unroll
    for (int i = 0; i < 4; ++i) {
      int idx = w * 4 + i;
      gl_lds16(tb + idx * 512 + l * 8, wtf + idx * 512);
    }
    // A fragments direct from bf16 global (L2-served)
    s8v a00 = *(const s8v*)(x0 + k0 + qd * 8);
    s8v a01 = *(const s8v*)(x0 + k0 + 32 + qd * 8);
    s8v a10 = *(const s8v*)(x1 + k0 + qd * 8);
    s8v a11 = *(const s8v*)(x1 + k0 + 32 + qd * 8);
    asm volatile("s_waitcnt vmcnt(0)" ::: "memory");
    __syncthreads();   // DMA landed for all waves
    #pragma unroll
    for (int cb = 0; cb < 8; ++cb) {
      s8v b0 = *(const s8v*)&wt[qd][cb * 16 + lm][0];
      s8v b1 = *(const s8v*)&wt[4 + qd][cb * 16 + lm][0];
      acc[cb][0] = MFMA_BF16(a00, b0, acc[cb][0], 0, 0, 0);
      acc[cb][0] = MFMA_BF16(a01, b1, acc[cb][0], 0, 0, 0);
      acc[cb][1] = MFMA_BF16(a10, b0, acc[cb][1], 0, 0, 0);
      acc[cb][1] = MFMA_BF16(a11, b1, acc[cb][1], 0, 0, 0);
    }
  }
  if (z == 0) {
    // Q: head-split [bh][s][d], pre-scaled
    #pragma unroll
    for (int cb = 0; cb < 8; ++cb) {
      int n = n0 + cb * 16 + lm;
      float bvv = bias[n];
      int hh = n >> 6, d = n & 63;
      #pragma unroll
      for (int ms = 0; ms < 2; ++ms) {
        #pragma unroll
        for (int r = 0; r < 4; ++r) {
          int m = m0 + w * 32 + ms * 16 + qd * 4 + r;
          int bidx = m >> 11, s = m & (SS - 1);
          qbuf[((long)(bidx * HH + hh) * SS + s) * HD + d] =
              f2bf((acc[cb][ms][r] + bvv) * SCALEQ);
        }
      }
    }
  } else if (z == 1) {
    // K -> ktile[bh][g][c][key][8]
    #pragma unroll
    for (int cb = 0; cb < 8; ++cb) {
      int n = n0 + cb * 16 + lm;
      float bvv = bias[n];
      int hh = n >> 6, d = n & 63;
      int c = d >> 3, e = d & 7;
      #pragma unroll
      for (int ms = 0; ms < 2; ++ms) {
        #pragma unroll
        for (int r = 0; r < 4; ++r) {
          int m = m0 + w * 32 + ms * 16 + qd * 4 + r;
          int bidx = m >> 11, s = m & (SS - 1);
          long bh = bidx * HH + hh;
          ktile[bh * KVB + (s >> 6) * 4096 + c * 512 + (s & 63) * 8 + e] =
              f2bf(acc[cb][ms][r] + bvv);
        }
      }
    }
  } else {
    // V -> vtile[bh][g][c][d][8], 4 consecutive s per 8B store
    #pragma unroll
    for (int cb = 0; cb < 8; ++cb) {
      int n = n0 + cb * 16 + lm;
      float bvv = bias[n];
      int hh = n >> 6, d = n & 63;
      #pragma unroll
      for (int ms = 0; ms < 2; ++ms) {
        int m = m0 + w * 32 + ms * 16 + qd * 4;
        int bidx = m >> 11, s = m & (SS - 1);
        long bh = bidx * HH + hh;
        unsigned short o4[4];
        #pragma unroll
        for (int r = 0; r < 4; ++r) o4[r] = f2bf(acc[cb][ms][r] + bvv);
        *(s4v*)&vtile[bh * KVB + (s >> 6) * 4096 + ((s & 63) >> 3) * 512 +
                      d * 8 + (s & 7)] = *(s4v*)o4;
      }
    }
  }
}

// ---------------------------------------------------------------------------
// Flash attention (round-7 base + permlane P-transpose + lazy max-reduce):
//  - P fragments built in-register via permlane{32,16}_swap (distinct
//    operands only — see mkfrag note). pbuf + its 2 lgkmcnt drains GONE.
//  - defer-max trigger uses per-group tm (__all spans the wave, so the
//    condition is EXACTLY equivalent); cross-group max shuffles run only
//    inside the rare rescale branch.
//  - mask from global/L1; K/V LDS-staged via gl_lds16 double-buffer.
// LDS = 66.5 KB, 2 blocks/CU. grid (16 q-blocks, 32 bh), block 256.
__global__ __launch_bounds__(256, 2) void attn(
    const unsigned short* __restrict__ qb, const unsigned short* __restrict__ ktile,
    const unsigned short* __restrict__ vtile, const float* __restrict__ tableF,
    const float* __restrict__ mkg, float* __restrict__ out) {
  __shared__ __align__(16) unsigned short ks[2][8][64][8];  // [buf][d-chunk][key][8d]
  __shared__ __align__(16) unsigned short vs[2][8][64][8];  // [buf][k-chunk][d][8k]
  __shared__ __align__(16) unsigned short qr2[NREL][130];   // [dist][q_local+pad]

  const int bh = blockIdx.y, b = bh >> 4, h = bh & 15;
  const int q0 = blockIdx.x * 128;
  const int t = threadIdx.x, w = t >> 6, l = t & 63;
  const int lm = l & 15, qd = l >> 4;
  const int qw = q0 + w * 32;          // this wave's q base (32 rows)
  const int qc0 = w * 32 + lm, qc1 = qc0 + 16;  // local q cols of the 2 subtiles

  const unsigned short* kkb = ktile + (long)bh * KVB;
  const unsigned short* vvb = vtile + (long)bh * KVB;

  // stage round 0 (key-group 0) into buf 0: lane-contiguous 1KB bursts
  #pragma unroll
  for (int i = 0; i < 2; ++i) {
    int c = 2 * w + i;
    gl_lds16(kkb + c * 512 + l * 8, &ks[0][c][0][0]);
    gl_lds16(vvb + c * 512 + l * 8, &vs[0][c][0][0]);
  }

  // Q fragments for both subtiles (q = qw + lm and qw + 16 + lm), pre-scaled
  const unsigned short* qrow = qb + ((long)bh * SS + qw + lm) * HD;
  const s8v qa0 = *(const s8v*)(qrow + qd * 8);
  const s8v qa1 = *(const s8v*)(qrow + 32 + qd * 8);
  const s8v qb0 = *(const s8v*)(qrow + 16 * HD + qd * 8);
  const s8v qb1 = *(const s8v*)(qrow + 16 * HD + 32 + qd * 8);

  // Fused qrel: qr2[dist][q_local] = q_scaled . table[dist], both subtiles
  #pragma unroll
  for (int cb = 0; cb < 9; ++cb) {
    int dist = cb * 16 + lm;
    int dc = dist > NREL - 1 ? NREL - 1 : dist;
    const float* trow = tableF + dc * HD;
    f4 t0 = *(const f4*)(trow + qd * 8);
    f4 t1 = *(const f4*)(trow + qd * 8 + 4);
    f4 t2 = *(const f4*)(trow + 32 + qd * 8);
    f4 t3 = *(const f4*)(trow + 32 + qd * 8 + 4);
    unsigned int tb[8];
    tb[0] = pk2bf(t0[0], t0[1]); tb[1] = pk2bf(t0[2], t0[3]);
    tb[2] = pk2bf(t1[0], t1[1]); tb[3] = pk2bf(t1[2], t1[3]);
    tb[4] = pk2bf(t2[0], t2[1]); tb[5] = pk2bf(t2[2], t2[3]);
    tb[6] = pk2bf(t3[0], t3[1]); tb[7] = pk2bf(t3[2], t3[3]);
    s8v b0 = *(s8v*)tb, b1 = *(s8v*)(tb + 4);
    f4 c0 = MFMA_BF16(qa0, b0, (f4)0.0f, 0, 0, 0);
    c0 = MFMA_BF16(qa1, b1, c0, 0, 0, 0);
    f4 c1 = MFMA_BF16(qb0, b0, (f4)0.0f, 0, 0, 0);
    c1 = MFMA_BF16(qb1, b1, c1, 0, 0, 0);
    if (dist <= NREL - 1) {
      #pragma unroll
      for (int r = 0; r < 4; ++r) {
        qr2[dist][w * 32 + qd * 4 + r] = f2bf(c0[r]);
        qr2[dist][w * 32 + 16 + qd * 4 + r] = f2bf(c1[r]);
      }
    }
  }
  asm volatile("s_waitcnt vmcnt(0)" ::: "memory");
  __syncthreads();

  const float bLo0 = bf2f(qr2[0][qc0]), bHi0 = bf2f(qr2[128][qc0]);
  const float bLo1 = bf2f(qr2[0][qc1]), bHi1 = bf2f(qr2[128][qc1]);
  const float* mrow = mkg + b * SS;               // mask*LOG2E (L1-resident)

  float m0_ = -1e30f, l0_ = 0.0f, m1_ = -1e30f, l1_ = 0.0f;
  f4 c40[4], c41[4];
  #pragma unroll
  for (int i = 0; i < 4; ++i) { c40[i] = (f4)0.0f; c41[i] = (f4)0.0f; }

  for (int rr = 0; rr < 32; ++rr) {
    const int kk = rr << 6;
    const int buf = rr & 1;
    if (rr < 31) {
      const int nb = buf ^ 1;
      const unsigned short* kg = kkb + (rr + 1) * 4096;
      const unsigned short* vg = vvb + (rr + 1) * 4096;
      #pragma unroll
      for (int i = 0; i < 2; ++i) {
        int c = 2 * w + i;
        gl_lds16(kg + c * 512 + l * 8, &ks[nb][c][0][0]);
        gl_lds16(vg + c * 512 + l * 8, &vs[nb][c][0][0]);
      }
    }
    // QK^T for both subtiles: K fragments read once, used twice
    f4 st0[4], st1[4];
    #pragma unroll
    for (int tt = 0; tt < 4; ++tt) {
      s8v k0v = *(const s8v*)&ks[buf][qd][tt * 16 + lm][0];
      s8v k1v = *(const s8v*)&ks[buf][4 + qd][tt * 16 + lm][0];
      st0[tt] = MFMA_BF16(k0v, qa0, (f4)0.0f, 0, 0, 0);
      st0[tt] = MFMA_BF16(k1v, qa1, st0[tt], 0, 0, 0);
      st1[tt] = MFMA_BF16(k0v, qb0, (f4)0.0f, 0, 0, 0);
      st1[tt] = MFMA_BF16(k1v, qb1, st1[tt], 0, 0, 0);
    }
    float z0[16], z1[16];
    const int kw = kk - qw;  // key-band offset relative to this wave's q range
    if (kw >= 96) {          // all dist >= 65 for this wave's 32 q
      #pragma unroll
      for (int tt = 0; tt < 4; ++tt) {
        f4 mv = *(const f4*)&mrow[kk + tt * 16 + qd * 4];
        #pragma unroll
        for (int r = 0; r < 4; ++r) {
          z0[tt * 4 + r] = st0[tt][r] + bHi0 + mv[r];
          z1[tt * 4 + r] = st1[tt][r] + bHi1 + mv[r];
        }
      }
    } else if (kw <= -128) { // all dist <= -65
      #pragma unroll
      for (int tt = 0; tt < 4; ++tt) {
        f4 mv = *(const f4*)&mrow[kk + tt * 16 + qd * 4];
        #pragma unroll
        for (int r = 0; r < 4; ++r) {
          z0[tt * 4 + r] = st0[tt][r] + bLo0 + mv[r];
          z1[tt * 4 + r] = st1[tt][r] + bLo1 + mv[r];
        }
      }
    } else {                 // diagonal band (3 iters/wave): LDS qrel lookups
      const int db0 = kw - lm + 64 + qd * 4;
      #pragma unroll
      for (int tt = 0; tt < 4; ++tt) {
        f4 mv = *(const f4*)&mrow[kk + tt * 16 + qd * 4];
        #pragma unroll
        for (int r = 0; r < 4; ++r) {
          int du = db0 + tt * 16 + r;
          int d0 = du < 0 ? 0 : (du > 128 ? 128 : du);
          int d1 = du - 16; d1 = d1 < 0 ? 0 : (d1 > 128 ? 128 : d1);
          z0[tt * 4 + r] = st0[tt][r] + bf2f(qr2[d0][qc0]) + mv[r];
          z1[tt * 4 + r] = st1[tt][r] + bf2f(qr2[d1][qc1]) + mv[r];
        }
      }
    }
    // defer-max with per-group tm: __all spans the wave, so the trigger is
    // exactly equivalent; cross-group max shuffles only on the rare rescale.
    float tm0 = z0[0], tm1 = z1[0];
    #pragma unroll
    for (int i = 1; i < 16; ++i) {
      tm0 = fmaxf(tm0, z0[i]);
      tm1 = fmaxf(tm1, z1[i]);
    }
    if (!__all(tm0 - m0_ <= 8.0f)) {
      tm0 = fmaxf(tm0, __shfl_xor(tm0, 16));
      tm0 = fmaxf(tm0, __shfl_xor(tm0, 32));
      float mn0 = fmaxf(m0_, tm0);
      float al0 = __builtin_amdgcn_exp2f(m0_ - mn0);
      m0_ = mn0; l0_ *= al0;
      #pragma unroll
      for (int db = 0; db < 4; ++db)
        #pragma unroll
        for (int r = 0; r < 4; ++r) c40[db][r] *= al0;
    }
    if (!__all(tm1 - m1_ <= 8.0f)) {
      tm1 = fmaxf(tm1, __shfl_xor(tm1, 16));
      tm1 = fmaxf(tm1, __shfl_xor(tm1, 32));
      float mn1 = fmaxf(m1_, tm1);
      float al1 = __builtin_amdgcn_exp2f(m1_ - mn1);
      m1_ = mn1; l1_ *= al1;
      #pragma unroll
      for (int db = 0; db < 4; ++db)
        #pragma unroll
        for (int r = 0; r < 4; ++r) c41[db][r] *= al1;
    }
    float s0 = 0.0f, s1 = 0.0f;
    #pragma unroll
    for (int i = 0; i < 16; ++i) {
      z0[i] = __builtin_amdgcn_exp2f(z0[i] - m0_); s0 += z0[i];
      z1[i] = __builtin_amdgcn_exp2f(z1[i] - m1_); s1 += z1[i];
    }
    s0 += __shfl_xor(s0, 16);
    s0 += __shfl_xor(s0, 32);
    s1 += __shfl_xor(s1, 16);
    s1 += __shfl_xor(s1, 32);
    l0_ += s0; l1_ += s1;

    // PV phase A (keys 0..31): P fragments built fully in-register
    {
      s8v pa0 = mkfrag(z0[0], z0[1], z0[2], z0[3], z0[4], z0[5], z0[6], z0[7]);
      s8v pa1 = mkfrag(z1[0], z1[1], z1[2], z1[3], z1[4], z1[5], z1[6], z1[7]);
      #pragma unroll
      for (int db = 0; db < 4; ++db) {
        s8v va = *(const s8v*)&vs[buf][qd][db * 16 + lm][0];
        c40[db] = MFMA_BF16(va, pa0, c40[db], 0, 0, 0);
        c41[db] = MFMA_BF16(va, pa1, c41[db], 0, 0, 0);
      }
    }
    // PV phase B (keys 32..63)
    {
      s8v pB0 = mkfrag(z0[8], z0[9], z0[10], z0[11], z0[12], z0[13], z0[14], z0[15]);
      s8v pB1 = mkfrag(z1[8], z1[9], z1[10], z1[11], z1[12], z1[13], z1[14], z1[15]);
      #pragma unroll
      for (int db = 0; db < 4; ++db) {
        s8v vb = *(const s8v*)&vs[buf][4 + qd][db * 16 + lm][0];
        c40[db] = MFMA_BF16(vb, pB0, c40[db], 0, 0, 0);
        c41[db] = MFMA_BF16(vb, pB1, c41[db], 0, 0, 0);
      }
    }
    asm volatile("s_waitcnt vmcnt(0)" ::: "memory");
    __syncthreads();
  }

  const float inv0 = 1.0f / l0_, inv1 = 1.0f / l1_;
  float* ob0 = out + ((long)b * SS + q0 + qc0) * DD + h * HD;
  float* ob1 = out + ((long)b * SS + q0 + qc1) * DD + h * HD;
  #pragma unroll
  for (int db = 0; db < 4; ++db) {
    f4 o0, o1;
    #pragma unroll
    for (int r = 0; r < 4; ++r) {
      o0[r] = c40[db][r] * inv0;
      o1[r] = c41[db][r] * inv1;
    }
    *(f4*)(ob0 + db * 16 + qd * 4) = o0;
    *(f4*)(ob1 + db * 16 + qd * 4) = o1;
  }
}

// ---------------------------------------------------------------------------
extern "C" void kernel_launch(void* const* d_in, const int* in_sizes, int n_in,
                              void* d_out, int out_size, void* d_ws, size_t ws_size,
                              hipStream_t stream) {
  const float* query = (const float*)d_in[0];
  const float* key   = (const float*)d_in[1];
  const float* value = (const float*)d_in[2];
  const float* mask  = (const float*)d_in[3];
  const float* Wq    = (const float*)d_in[4];
  const float* bq    = (const float*)d_in[5];
  const float* Wk    = (const float*)d_in[6];
  const float* bk    = (const float*)d_in[7];
  const float* Wv    = (const float*)d_in[8];
  const float* bv    = (const float*)d_in[9];
  const float* table = (const float*)d_in[10];

  char* ws = (char*)d_ws;
  // workspace layout (bytes), span 56 MB
  unsigned short* WTt   = (unsigned short*)(ws);               // 6,291,456 (tiled)
  float*          mkg   = (float*)(ws + (7l << 20));           // 16 KB mask*LOG2E
  unsigned short* Xb    = (unsigned short*)(ws + (8l << 20));  // 25,165,824
  unsigned short* qbuf  = (unsigned short*)(ws + (32l << 20));
  unsigned short* ktile = (unsigned short*)(ws + (40l << 20));
  unsigned short* vtile = (unsigned short*)(ws + (48l << 20));

  // 1) convert inputs fp32 -> bf16 (once); pre-scale mask
  cvt_x<<<dim3(2048, 3, 1), 256, 0, stream>>>(query, key, value, mask, Xb, mkg);

  // 2) transpose+convert weights into proj's tiled LDS image
  cvt_w<<<dim3(16, 16, 3), 256, 0, stream>>>(Wq, Wk, Wv, WTt);

  // 3) fused QKV projections; K/V written as attn's tiled LDS images
  proj_gemm<<<dim3(8, 32, 3), 256, 0, stream>>>(Xb, WTt, bq, bk, bv,
                                                qbuf, ktile, vtile);

  // 4) flash attention: permlane P-transpose (no pbuf), lazy max-reduce
  attn<<<dim3(16, 32, 1), 256, 0, stream>>>(qbuf, ktile, vtile, table,
                                            mkg, (float*)d_out);
}